// Round 1
// baseline (330.449 us; speedup 1.0000x reference)
//
#include <hip/hip_runtime.h>

#define NROWS   262144
#define DIN     480
#define DOUT    480
#define NS      224
#define LDW0    224

#define M_TILE    32
#define XS_STRIDE 488   // bf16 elems per LDS row (480 + 8 pad -> 2-way banks, 16B aligned)
#define GS_STRIDE 97

#define CST_SILU 1.6765290f            // analytic 1/sqrt(E[silu(x)^2]), x~N(0,1)
#define CST_RELU 1.4142135623730951f   // analytic 1/sqrt(E[relu(x)^2]) = sqrt(2)
#define INV_S128 0.08838834764831845f
#define INV_S64  0.125f
#define INV_S32  0.17677669529663687f

typedef short bf16x8 __attribute__((ext_vector_type(8)));
typedef float f32x4  __attribute__((ext_vector_type(4)));

__device__ __forceinline__ ushort f2bf(float f) {
    unsigned u = __float_as_uint(f);
    u = (u + 0x7FFFu + ((u >> 16) & 1u)) >> 16;   // RNE
    return (ushort)u;
}

// B fragment for mfma_f32_16x16x32_bf16: lane holds col n = nbase+(lane&15),
// k = kbase + 8*(lane>>4) + e  (e = 0..7), from row-major f32 weight W[k][n].
__device__ __forceinline__ bf16x8 load_b_frag(const float* __restrict__ W, int ldw,
                                              int kbase, int nbase, int lane) {
    int n  = nbase + (lane & 15);
    int k0 = kbase + ((lane >> 4) << 3);
    bf16x8 f;
#pragma unroll
    for (int e = 0; e < 8; ++e) f[e] = (short)f2bf(W[(k0 + e) * ldw + n]);
    return f;
}

__global__ __launch_bounds__(256) void percep_kernel(
        const float* __restrict__ x,  const float* __restrict__ W0,
        const float* __restrict__ b0, const float* __restrict__ W1,
        const float* __restrict__ W2, float* __restrict__ out) {
    __shared__ __align__(16) ushort xs[M_TILE * XS_STRIDE];
    __shared__ float gates[M_TILE * GS_STRIDE];

    const int tid  = threadIdx.x;
    const int lane = tid & 63;
    const int wid  = tid >> 6;
    const int lr   = lane & 15;   // A row / B,D col within 16-tile
    const int kg   = lane >> 4;   // k-group / D row-group
    const long row0 = (long)blockIdx.x * M_TILE;

    // ---- stage x tile -> LDS bf16, deinterleaved so A-frags are contiguous ----
    // x1[n,i,m] = x[n,128+3i+m] -> xs col 128 + 64m + i   (K-dim contiguous)
    // x2[n,i,m] = x[n,320+5i+m] -> xs col 320 + 32m + i
    for (int idx = tid; idx < M_TILE * (DIN / 4); idx += 256) {
        int row = idx / (DIN / 4);
        int c4  = idx - row * (DIN / 4);
        const float4 v4 = reinterpret_cast<const float4*>(x + (row0 + row) * DIN)[c4];
        float vals[4] = {v4.x, v4.y, v4.z, v4.w};
        int c = c4 * 4;
#pragma unroll
        for (int e = 0; e < 4; ++e) {
            int cc = c + e, tc;
            if (cc < 128)      tc = cc;
            else if (cc < 320) { int d = cc - 128; tc = 128 + (d % 3) * 64 + d / 3; }
            else               { int d = cc - 320; tc = 320 + (d % 5) * 32 + d / 5; }
            xs[row * XS_STRIDE + tc] = f2bf(vals[e]);
        }
    }
    __syncthreads();

    // ---- per-wave ownership ----
    // w0: S-tiles 0-3 (silu) + V j-tile 0      w1: S 4-7 (silu) + V 1
    // w2: S 8-10 (gates)     + V 2 + T 0       w3: S 11-13 (gates) + V 3 + T 1
    int sbase, scount, vu, tu;
    if      (wid == 0) { sbase = 0;  scount = 4; vu = 0; tu = -1; }
    else if (wid == 1) { sbase = 4;  scount = 4; vu = 1; tu = -1; }
    else if (wid == 2) { sbase = 8;  scount = 3; vu = 2; tu = 0;  }
    else               { sbase = 11; scount = 3; vu = 3; tu = 1;  }

    // ---- S GEMM: (32x128) @ (128x224) ----
    for (int t = 0; t < scount; ++t) {
        int st = sbase + t;
        bf16x8 b[4];
#pragma unroll
        for (int kk = 0; kk < 4; ++kk) b[kk] = load_b_frag(W0, LDW0, kk * 32, st * 16, lane);
        int col = st * 16 + lr;
        float bias = b0[col];
#pragma unroll
        for (int rf = 0; rf < 2; ++rf) {
            f32x4 acc = {0.f, 0.f, 0.f, 0.f};
#pragma unroll
            for (int kk = 0; kk < 4; ++kk) {
                const bf16x8 a = *reinterpret_cast<const bf16x8*>(
                    &xs[(rf * 16 + lr) * XS_STRIDE + kk * 32 + (kg << 3)]);
                acc = __builtin_amdgcn_mfma_f32_16x16x32_bf16(a, b[kk], acc, 0, 0, 0);
            }
            int rbase = rf * 16 + (kg << 2);
            if (st < 8) {            // silu scalars -> global (coalesced 64B segs)
#pragma unroll
                for (int r = 0; r < 4; ++r) {
                    float s = acc[r] * INV_S128 + bias;
                    float val = CST_SILU * s / (1.f + __expf(-s));
                    out[(row0 + rbase + r) * DOUT + col] = val;
                }
            } else {                 // relu gates -> LDS
#pragma unroll
                for (int r = 0; r < 4; ++r) {
                    float s = acc[r] * INV_S128 + bias;
                    gates[(rbase + r) * GS_STRIDE + (col - 128)] = CST_RELU * fmaxf(s, 0.f);
                }
            }
        }
    }

    // ---- V GEMMs: 3x (32x64)@(64x64), shared W1 B-frags ----
    f32x4 vacc[2][3];
    {
        bf16x8 bv[2];
#pragma unroll
        for (int kk = 0; kk < 2; ++kk) bv[kk] = load_b_frag(W1, 64, kk * 32, vu * 16, lane);
#pragma unroll
        for (int rf = 0; rf < 2; ++rf)
#pragma unroll
            for (int m = 0; m < 3; ++m) {
                f32x4 acc = {0.f, 0.f, 0.f, 0.f};
#pragma unroll
                for (int kk = 0; kk < 2; ++kk) {
                    const bf16x8 a = *reinterpret_cast<const bf16x8*>(
                        &xs[(rf * 16 + lr) * XS_STRIDE + 128 + m * 64 + kk * 32 + (kg << 3)]);
                    acc = __builtin_amdgcn_mfma_f32_16x16x32_bf16(a, bv[kk], acc, 0, 0, 0);
                }
#pragma unroll
                for (int r = 0; r < 4; ++r) acc[r] *= INV_S64;
                vacc[rf][m] = acc;
            }
    }

    // ---- T GEMMs: 5x (32x32)@(32x32), shared W2 B-frag, K=32 = one MFMA ----
    f32x4 tacc[2][5];
    if (tu >= 0) {
        bf16x8 bt = load_b_frag(W2, 32, 0, tu * 16, lane);
#pragma unroll
        for (int rf = 0; rf < 2; ++rf)
#pragma unroll
            for (int m = 0; m < 5; ++m) {
                const bf16x8 a = *reinterpret_cast<const bf16x8*>(
                    &xs[(rf * 16 + lr) * XS_STRIDE + 320 + m * 32 + (kg << 3)]);
                f32x4 z = {0.f, 0.f, 0.f, 0.f};
                f32x4 acc = __builtin_amdgcn_mfma_f32_16x16x32_bf16(a, bt, z, 0, 0, 0);
#pragma unroll
                for (int r = 0; r < 4; ++r) acc[r] *= INV_S32;
                tacc[rf][m] = acc;
            }
    }

    __syncthreads();   // gates ready

    // ---- gated stores: out[:,128+3j+m] = v_m[:,j]*g[j]; out[:,320+5j+m] = t_m[:,j]*g[64+j]
    {
        int j = vu * 16 + lr;
#pragma unroll
        for (int rf = 0; rf < 2; ++rf)
#pragma unroll
            for (int r = 0; r < 4; ++r) {
                int row = rf * 16 + (kg << 2) + r;
                float g = gates[row * GS_STRIDE + j];
                float* po = out + (row0 + row) * DOUT + 128 + 3 * j;
#pragma unroll
                for (int m = 0; m < 3; ++m) po[m] = vacc[rf][m][r] * g;
            }
    }
    if (tu >= 0) {
        int j = tu * 16 + lr;
#pragma unroll
        for (int rf = 0; rf < 2; ++rf)
#pragma unroll
            for (int r = 0; r < 4; ++r) {
                int row = rf * 16 + (kg << 2) + r;
                float g = gates[row * GS_STRIDE + 64 + j];
                float* po = out + (row0 + row) * DOUT + 320 + 5 * j;
#pragma unroll
                for (int m = 0; m < 5; ++m) po[m] = tacc[rf][m][r] * g;
            }
    }
}

extern "C" void kernel_launch(void* const* d_in, const int* in_sizes, int n_in,
                              void* d_out, int out_size, void* d_ws, size_t ws_size,
                              hipStream_t stream) {
    const float* x  = (const float*)d_in[0];
    const float* W0 = (const float*)d_in[1];
    const float* b0 = (const float*)d_in[2];
    const float* W1 = (const float*)d_in[3];
    const float* W2 = (const float*)d_in[4];
    float* out = (float*)d_out;
    dim3 grid(NROWS / M_TILE), block(256);
    hipLaunchKernelGGL(percep_kernel, grid, block, 0, stream, x, W0, b0, W1, W2, out);
}

// Round 2
// 224.184 us; speedup vs baseline: 1.4740x; 1.4740x over previous
//
#include <hip/hip_runtime.h>

#define NROWS   262144
#define DIN     480
#define DOUT    480
#define LDW0    224

#define M_TILE  32
#define XSTR    488     // ushort stride; 976B/row = 2-way banks for b128 reads

#define CST_SILU 1.6765290f
#define CST_RELU 1.4142135623730951f
#define INV_S128 0.08838834764831845f
#define INV_S64  0.125f
#define INV_S32  0.17677669529663687f

// ws fragment layout (bf16x8 per lane, 1024B per fragment):
//   frag id: W0 tile t(0..13) kk(0..3) -> t*4+kk   (0..55)
//            W1 vu(0..3) kk(0..1)      -> 56+vu*2+kk (56..63)
//            W2 tu(0..1)               -> 64+tu      (64..65)
#define WS_FRAGS 66
#define WS_BYTES (WS_FRAGS * 64 * 16)

typedef short  bf16x8 __attribute__((ext_vector_type(8)));
typedef short  s16x4  __attribute__((ext_vector_type(4)));
typedef float  f32x4  __attribute__((ext_vector_type(4)));

__device__ __forceinline__ ushort f2bf(float f) {
    unsigned u = __float_as_uint(f);
    u = (u + 0x7FFFu + ((u >> 16) & 1u)) >> 16;   // RNE
    return (ushort)u;
}
__device__ __forceinline__ float bf2f(ushort h) {
    return __uint_as_float(((unsigned)h) << 16);
}

// fallback: build B frag from f32 weights (row-major W[k][n])
__device__ __forceinline__ bf16x8 load_b_frag(const float* __restrict__ W, int ldw,
                                              int kbase, int nbase, int lane) {
    int n  = nbase + (lane & 15);
    int k0 = kbase + ((lane >> 4) << 3);
    bf16x8 f;
#pragma unroll
    for (int e = 0; e < 8; ++e) f[e] = (short)f2bf(W[(k0 + e) * ldw + n]);
    return f;
}

__global__ __launch_bounds__(64) void prep_frags(
        const float* __restrict__ W0, const float* __restrict__ W1,
        const float* __restrict__ W2, ushort* __restrict__ ws) {
    const int b = blockIdx.x, lane = threadIdx.x;
    const int lr = lane & 15, kg = lane >> 4;
    const float* W; int ldw, n, k0;
    if (b < 56)      { W = W0; ldw = 224; n = (b >> 2) * 16 + lr; k0 = (b & 3) * 32 + (kg << 3); }
    else if (b < 64) { int t = b - 56; W = W1; ldw = 64; n = (t >> 1) * 16 + lr; k0 = (t & 1) * 32 + (kg << 3); }
    else             { W = W2; ldw = 32; n = (b - 64) * 16 + lr; k0 = (kg << 3); }
    bf16x8 f;
#pragma unroll
    for (int e = 0; e < 8; ++e) f[e] = (short)f2bf(W[(k0 + e) * ldw + n]);
    *reinterpret_cast<bf16x8*>(ws + (b * 64 + lane) * 8) = f;
}

template <bool PRE>
__global__ __launch_bounds__(256, 5) void percep_kernel(
        const float* __restrict__ x,  const float* __restrict__ W0,
        const float* __restrict__ b0, const float* __restrict__ W1,
        const float* __restrict__ W2, float* __restrict__ out,
        const ushort* __restrict__ ws) {
    __shared__ __align__(16) ushort xs[M_TILE * XSTR];   // 31232 B -> 5 blocks/CU

    const int tid  = threadIdx.x;
    const int lane = tid & 63;
    const int wid  = tid >> 6;
    const int lr   = lane & 15;
    const int kg   = lane >> 4;
    const int row0 = blockIdx.x * M_TILE;
    const bf16x8* F = reinterpret_cast<const bf16x8*>(ws);

    // ---------- stage x -> LDS bf16, all index math compile-time ----------
    // region 0: cols 0..127 straight copy
#pragma unroll
    for (int it = 0; it < 4; ++it) {
        int idx = tid + it * 256;
        int row = idx >> 5, c4 = idx & 31;
        const float4 v = reinterpret_cast<const float4*>(x + (row0 + row) * DIN)[c4];
        s16x4 o = { (short)f2bf(v.x), (short)f2bf(v.y), (short)f2bf(v.z), (short)f2bf(v.w) };
        *reinterpret_cast<s16x4*>(&xs[row * XSTR + c4 * 4]) = o;
    }
    // region 1: src cols 128+12g..139+12g -> m=j%3, i=4g+j/3 at col 128+64m+i
#pragma unroll
    for (int it = 0; it < 2; ++it) {
        int idx = tid + it * 256;
        int row = idx >> 4, g = idx & 15;
        const float4* p = reinterpret_cast<const float4*>(x + (row0 + row) * DIN + 128 + 12 * g);
        float4 q0 = p[0], q1 = p[1], q2 = p[2];
        float v[12] = { q0.x, q0.y, q0.z, q0.w, q1.x, q1.y, q1.z, q1.w, q2.x, q2.y, q2.z, q2.w };
#pragma unroll
        for (int m = 0; m < 3; ++m) {
            s16x4 o = { (short)f2bf(v[m]), (short)f2bf(v[m + 3]),
                        (short)f2bf(v[m + 6]), (short)f2bf(v[m + 9]) };
            *reinterpret_cast<s16x4*>(&xs[row * XSTR + 128 + 64 * m + 4 * g]) = o;
        }
    }
    // region 2: src cols 320+20g.. -> m=j%5, i=4g+j/5 at col 320+32m+i
    {
        int row = tid >> 3, g = tid & 7;
        const float4* p = reinterpret_cast<const float4*>(x + (row0 + row) * DIN + 320 + 20 * g);
        float4 q0 = p[0], q1 = p[1], q2 = p[2], q3 = p[3], q4 = p[4];
        float v[20] = { q0.x, q0.y, q0.z, q0.w, q1.x, q1.y, q1.z, q1.w, q2.x, q2.y, q2.z, q2.w,
                        q3.x, q3.y, q3.z, q3.w, q4.x, q4.y, q4.z, q4.w };
#pragma unroll
        for (int m = 0; m < 5; ++m) {
            s16x4 o = { (short)f2bf(v[m]), (short)f2bf(v[m + 5]),
                        (short)f2bf(v[m + 10]), (short)f2bf(v[m + 15]) };
            *reinterpret_cast<s16x4*>(&xs[row * XSTR + 320 + 32 * m + 4 * g]) = o;
        }
    }
    __syncthreads();

    // ---------- hoist S A-frags to registers (x0 region becomes dead after) ----------
    bf16x8 aS[2][4];
#pragma unroll
    for (int rf = 0; rf < 2; ++rf)
#pragma unroll
        for (int kk = 0; kk < 4; ++kk)
            aS[rf][kk] = *reinterpret_cast<const bf16x8*>(
                &xs[(rf * 16 + lr) * XSTR + kk * 32 + (kg << 3)]);
    __syncthreads();   // all region-0 reads done; gates may overwrite cols 0..95

    // wave ownership: w0/w1 silu tiles, w2/w3 gate tiles + T
    int sbase, scount, vu, tu;
    if      (wid == 0) { sbase = 0;  scount = 4; vu = 0; tu = -1; }
    else if (wid == 1) { sbase = 4;  scount = 4; vu = 1; tu = -1; }
    else if (wid == 2) { sbase = 8;  scount = 3; vu = 2; tu = 0;  }
    else               { sbase = 11; scount = 3; vu = 3; tu = 1;  }

    // ---------- S: (32x128)@(128x224), silu -> out, relu gates -> xs[.., 0..95] ----------
    for (int t = 0; t < scount; ++t) {
        int st  = sbase + t;
        int col = st * 16 + lr;
        bf16x8 bS[4];
#pragma unroll
        for (int kk = 0; kk < 4; ++kk)
            bS[kk] = PRE ? F[(st * 4 + kk) * 64 + lane]
                         : load_b_frag(W0, LDW0, kk * 32, st * 16, lane);
        float bias = b0[col];
#pragma unroll
        for (int rf = 0; rf < 2; ++rf) {
            f32x4 acc = { 0.f, 0.f, 0.f, 0.f };
#pragma unroll
            for (int kk = 0; kk < 4; ++kk)
                acc = __builtin_amdgcn_mfma_f32_16x16x32_bf16(aS[rf][kk], bS[kk], acc, 0, 0, 0);
            int rbase = rf * 16 + (kg << 2);
            if (st < 8) {
#pragma unroll
                for (int r = 0; r < 4; ++r) {
                    float s = acc[r] * INV_S128 + bias;
                    out[(row0 + rbase + r) * DOUT + col] = CST_SILU * s / (1.f + __expf(-s));
                }
            } else {
#pragma unroll
                for (int r = 0; r < 4; ++r) {
                    float s = acc[r] * INV_S128 + bias;
                    xs[(rbase + r) * XSTR + (col - 128)] = f2bf(CST_RELU * fmaxf(s, 0.f));
                }
            }
        }
    }
    __syncthreads();   // gates ready

    // ---------- V: 3x (32x64)@(64x64), gate j = vu*16+lr ----------
    {
        bf16x8 bV[2];
#pragma unroll
        for (int kk = 0; kk < 2; ++kk)
            bV[kk] = PRE ? F[(56 + vu * 2 + kk) * 64 + lane]
                         : load_b_frag(W1, 64, kk * 32, vu * 16, lane);
        int j = vu * 16 + lr;
#pragma unroll
        for (int rf = 0; rf < 2; ++rf) {
            f32x4 acc0 = {0,0,0,0}, acc1 = {0,0,0,0}, acc2 = {0,0,0,0};
#pragma unroll
            for (int kk = 0; kk < 2; ++kk) {
                const ushort* base = &xs[(rf * 16 + lr) * XSTR + 128 + kk * 32 + (kg << 3)];
                acc0 = __builtin_amdgcn_mfma_f32_16x16x32_bf16(
                    *reinterpret_cast<const bf16x8*>(base +   0), bV[kk], acc0, 0, 0, 0);
                acc1 = __builtin_amdgcn_mfma_f32_16x16x32_bf16(
                    *reinterpret_cast<const bf16x8*>(base +  64), bV[kk], acc1, 0, 0, 0);
                acc2 = __builtin_amdgcn_mfma_f32_16x16x32_bf16(
                    *reinterpret_cast<const bf16x8*>(base + 128), bV[kk], acc2, 0, 0, 0);
            }
#pragma unroll
            for (int r = 0; r < 4; ++r) {
                int row = rf * 16 + (kg << 2) + r;
                float g = bf2f(xs[row * XSTR + j]) * INV_S64;
                float* po = out + (row0 + row) * DOUT + 128 + 3 * j;
                po[0] = acc0[r] * g; po[1] = acc1[r] * g; po[2] = acc2[r] * g;
            }
        }
    }

    // ---------- T: 5x (32x32)@(32x32), gate 64 + tu*16+lr ----------
    if (tu >= 0) {
        bf16x8 bT = PRE ? F[(64 + tu) * 64 + lane]
                        : load_b_frag(W2, 32, 0, tu * 16, lane);
        int j = tu * 16 + lr;
#pragma unroll
        for (int rf = 0; rf < 2; ++rf) {
            const ushort* base = &xs[(rf * 16 + lr) * XSTR + 320 + (kg << 3)];
            f32x4 z = {0,0,0,0};
            f32x4 a0 = __builtin_amdgcn_mfma_f32_16x16x32_bf16(*reinterpret_cast<const bf16x8*>(base +   0), bT, z, 0, 0, 0);
            f32x4 a1 = __builtin_amdgcn_mfma_f32_16x16x32_bf16(*reinterpret_cast<const bf16x8*>(base +  32), bT, z, 0, 0, 0);
            f32x4 a2 = __builtin_amdgcn_mfma_f32_16x16x32_bf16(*reinterpret_cast<const bf16x8*>(base +  64), bT, z, 0, 0, 0);
            f32x4 a3 = __builtin_amdgcn_mfma_f32_16x16x32_bf16(*reinterpret_cast<const bf16x8*>(base +  96), bT, z, 0, 0, 0);
            f32x4 a4 = __builtin_amdgcn_mfma_f32_16x16x32_bf16(*reinterpret_cast<const bf16x8*>(base + 128), bT, z, 0, 0, 0);
#pragma unroll
            for (int r = 0; r < 4; ++r) {
                int row = rf * 16 + (kg << 2) + r;
                float g = bf2f(xs[row * XSTR + 64 + j]) * INV_S32;
                float* po = out + (row0 + row) * DOUT + 320 + 5 * j;
                po[0] = a0[r] * g; po[1] = a1[r] * g; po[2] = a2[r] * g;
                po[3] = a3[r] * g; po[4] = a4[r] * g;
            }
        }
    }
}

extern "C" void kernel_launch(void* const* d_in, const int* in_sizes, int n_in,
                              void* d_out, int out_size, void* d_ws, size_t ws_size,
                              hipStream_t stream) {
    const float* x  = (const float*)d_in[0];
    const float* W0 = (const float*)d_in[1];
    const float* b0 = (const float*)d_in[2];
    const float* W1 = (const float*)d_in[3];
    const float* W2 = (const float*)d_in[4];
    float* out = (float*)d_out;
    dim3 grid(NROWS / M_TILE), block(256);
    if (ws_size >= WS_BYTES) {
        hipLaunchKernelGGL(prep_frags, dim3(WS_FRAGS), dim3(64), 0, stream, W0, W1, W2, (ushort*)d_ws);
        hipLaunchKernelGGL((percep_kernel<true>), grid, block, 0, stream,
                           x, W0, b0, W1, W2, out, (const ushort*)d_ws);
    } else {
        hipLaunchKernelGGL((percep_kernel<false>), grid, block, 0, stream,
                           x, W0, b0, W1, W2, out, (const ushort*)d_ws);
    }
}